// Round 1
// baseline (111.207 us; speedup 1.0000x reference)
//
#include <hip/hip_runtime.h>

#define H_DIM 1024
#define W_DIM 1024
#define EPS 1e-6f

// x_v[h,w] = -10*x[h-2,w] - x[h-1,w] + x[h+1,w] + 10*x[h+2,w]   (zero pad)
// x_h[h,w] = -10*x[h,w-2] - x[h,w-1] + x[h,w+1] + 10*x[h,w+2]   (zero pad)
// out = sqrt(x_v^2 + x_h^2 + EPS)

__global__ __launch_bounds__(256) void grad_mag_kernel(
    const float* __restrict__ x, float* __restrict__ out) {
    const int tid   = threadIdx.x;
    const int h     = blockIdx.y;
    const int plane = blockIdx.z;
    const int w0    = (blockIdx.x * 256 + tid) * 4;
    if (w0 >= W_DIM) return;

    const size_t planeOff = (size_t)plane * H_DIM * W_DIM;
    const float* xp = x + planeOff;
    float*       op = out + planeOff;
    const size_t rowOff = (size_t)h * W_DIM + w0;

    // center row vector
    const float4 c = *reinterpret_cast<const float4*>(xp + rowOff);

    // vertical neighbor rows (zero-padded)
    float4 vm2 = make_float4(0.f, 0.f, 0.f, 0.f);
    float4 vm1 = vm2, vp1 = vm2, vp2 = vm2;
    if (h >= 2)        vm2 = *reinterpret_cast<const float4*>(xp + rowOff - 2 * W_DIM);
    if (h >= 1)        vm1 = *reinterpret_cast<const float4*>(xp + rowOff - 1 * W_DIM);
    if (h + 1 < H_DIM) vp1 = *reinterpret_cast<const float4*>(xp + rowOff + 1 * W_DIM);
    if (h + 2 < H_DIM) vp2 = *reinterpret_cast<const float4*>(xp + rowOff + 2 * W_DIM);

    float4 xv;
    xv.x = -10.f * vm2.x - vm1.x + vp1.x + 10.f * vp2.x;
    xv.y = -10.f * vm2.y - vm1.y + vp1.y + 10.f * vp2.y;
    xv.z = -10.f * vm2.z - vm1.z + vp1.z + 10.f * vp2.z;
    xv.w = -10.f * vm2.w - vm1.w + vp1.w + 10.f * vp2.w;

    // horizontal neighbors: need x[h, w0-2], x[h, w0-1], x[h, w0+4], x[h, w0+5]
    const float* row = xp + (size_t)h * W_DIM;
    float wl2 = (w0 >= 2)        ? row[w0 - 2] : 0.f;
    float wl1 = (w0 >= 1)        ? row[w0 - 1] : 0.f;
    float wr4 = (w0 + 4 < W_DIM) ? row[w0 + 4] : 0.f;
    float wr5 = (w0 + 5 < W_DIM) ? row[w0 + 5] : 0.f;

    float4 xh;
    xh.x = -10.f * wl2 - wl1 + c.y + 10.f * c.z;
    xh.y = -10.f * wl1 - c.x + c.z + 10.f * c.w;
    xh.z = -10.f * c.x - c.y + c.w + 10.f * wr4;
    xh.w = -10.f * c.y - c.z + wr4 + 10.f * wr5;

    float4 o;
    o.x = sqrtf(xv.x * xv.x + xh.x * xh.x + EPS);
    o.y = sqrtf(xv.y * xv.y + xh.y * xh.y + EPS);
    o.z = sqrtf(xv.z * xv.z + xh.z * xh.z + EPS);
    o.w = sqrtf(xv.w * xv.w + xh.w * xh.w + EPS);

    *reinterpret_cast<float4*>(op + rowOff) = o;
}

extern "C" void kernel_launch(void* const* d_in, const int* in_sizes, int n_in,
                              void* d_out, int out_size, void* d_ws, size_t ws_size,
                              hipStream_t stream) {
    const float* x   = (const float*)d_in[0];
    float*       out = (float*)d_out;
    const int planes = in_sizes[0] / (H_DIM * W_DIM);  // 16*2 = 32

    dim3 block(256, 1, 1);
    dim3 grid(W_DIM / (4 * 256), H_DIM, planes);  // (1, 1024, 32)
    grad_mag_kernel<<<grid, block, 0, stream>>>(x, out);
}

// Round 2
// 51.020 us; speedup vs baseline: 2.1797x; 2.1797x over previous
//
#include <hip/hip_runtime.h>

#define H_DIM 1024
#define W_DIM 1024
#define EPS 1e-6f
#define R_ROWS 16

// x_v[h,w] = -10*x[h-2,w] - x[h-1,w] + x[h+1,w] + 10*x[h+2,w]   (zero pad)
// x_h[h,w] = -10*x[h,w-2] - x[h,w-1] + x[h,w+1] + 10*x[h,w+2]   (zero pad)
// out = sqrt(x_v^2 + x_h^2 + EPS)
//
// Each thread: 4 contiguous columns (float4) x R_ROWS rows, 5-row register
// sliding window (fully unrolled -> static indexing, stays in VGPRs).

__global__ __launch_bounds__(256) void grad_mag_kernel(
    const float* __restrict__ x, float* __restrict__ out) {
    const int tid = threadIdx.x;
    const int w0  = tid * 4;                 // 256 threads * 4 = 1024 = full row
    const int h0  = blockIdx.y * R_ROWS;
    const size_t planeOff = (size_t)blockIdx.z * (size_t)(H_DIM * W_DIM);
    const float* __restrict__ xp = x + planeOff;
    float*       __restrict__ op = out + planeOff;

    float4 win[5];   // row vectors
    float4 edg[5];   // x: row[w0-2], y: row[w0-1], z: row[w0+4], w: row[w0+5]

    auto loadRow = [&](int h, float4& v, float4& e) {
        if (h >= 0 && h < H_DIM) {
            const float* row = xp + (size_t)h * W_DIM;
            v = *reinterpret_cast<const float4*>(row + w0);
            e.x = (w0 >= 2)         ? row[w0 - 2] : 0.f;
            e.y = (w0 >= 1)         ? row[w0 - 1] : 0.f;
            e.z = (w0 + 4 < W_DIM)  ? row[w0 + 4] : 0.f;
            e.w = (w0 + 5 < W_DIM)  ? row[w0 + 5] : 0.f;
        } else {
            v = make_float4(0.f, 0.f, 0.f, 0.f);
            e = make_float4(0.f, 0.f, 0.f, 0.f);
        }
    };

    // Preload rows h0-2 .. h0+1 into window slots 0..3
    loadRow(h0 - 2, win[0], edg[0]);
    loadRow(h0 - 1, win[1], edg[1]);
    loadRow(h0 + 0, win[2], edg[2]);
    loadRow(h0 + 1, win[3], edg[3]);

    #pragma unroll
    for (int i = 0; i < R_ROWS; ++i) {
        // bring in row h0+i+2 (the "+2" tap for output row h0+i)
        loadRow(h0 + i + 2, win[(i + 4) % 5], edg[(i + 4) % 5]);

        const float4 m2 = win[(i + 0) % 5];
        const float4 m1 = win[(i + 1) % 5];
        const float4 c  = win[(i + 2) % 5];
        const float4 p1 = win[(i + 3) % 5];
        const float4 p2 = win[(i + 4) % 5];
        const float4 e  = edg[(i + 2) % 5];

        float4 xv;
        xv.x = -10.f * m2.x - m1.x + p1.x + 10.f * p2.x;
        xv.y = -10.f * m2.y - m1.y + p1.y + 10.f * p2.y;
        xv.z = -10.f * m2.z - m1.z + p1.z + 10.f * p2.z;
        xv.w = -10.f * m2.w - m1.w + p1.w + 10.f * p2.w;

        float4 xh;
        xh.x = -10.f * e.x - e.y + c.y + 10.f * c.z;
        xh.y = -10.f * e.y - c.x + c.z + 10.f * c.w;
        xh.z = -10.f * c.x - c.y + c.w + 10.f * e.z;
        xh.w = -10.f * c.y - c.z + e.z + 10.f * e.w;

        float4 o;
        o.x = sqrtf(xv.x * xv.x + xh.x * xh.x + EPS);
        o.y = sqrtf(xv.y * xv.y + xh.y * xh.y + EPS);
        o.z = sqrtf(xv.z * xv.z + xh.z * xh.z + EPS);
        o.w = sqrtf(xv.w * xv.w + xh.w * xh.w + EPS);

        *reinterpret_cast<float4*>(op + (size_t)(h0 + i) * W_DIM + w0) = o;
    }
}

extern "C" void kernel_launch(void* const* d_in, const int* in_sizes, int n_in,
                              void* d_out, int out_size, void* d_ws, size_t ws_size,
                              hipStream_t stream) {
    const float* x   = (const float*)d_in[0];
    float*       out = (float*)d_out;
    const int planes = in_sizes[0] / (H_DIM * W_DIM);  // 16*2 = 32

    dim3 block(256, 1, 1);
    dim3 grid(1, H_DIM / R_ROWS, planes);  // (1, 64, 32)
    grad_mag_kernel<<<grid, block, 0, stream>>>(x, out);
}